// Round 5
// baseline (133.632 us; speedup 1.0000x reference)
//
#include <hip/hip_runtime.h>
#include <math.h>

#define NN 256
#define DD 128
#define GRID 256

typedef float4 f4;

// acc += s * v (componentwise)
#define FMA4(acc, s, v)                          \
  acc.x = fmaf(s, v.x, acc.x);                   \
  acc.y = fmaf(s, v.y, acc.y);                   \
  acc.z = fmaf(s, v.z, acc.z);                   \
  acc.w = fmaf(s, v.w, acc.w);

// acc += a * relu(p + v)
#define FMA4R(acc, a, p, v)                              \
  acc.x = fmaf(a, fmaxf(p.x + v.x, 0.f), acc.x);         \
  acc.y = fmaf(a, fmaxf(p.y + v.y, 0.f), acc.y);         \
  acc.z = fmaf(a, fmaxf(p.z + v.z, 0.f), acc.z);         \
  acc.w = fmaf(a, fmaxf(p.w + v.w, 0.f), acc.w);

#define ZERO4 {0.f, 0.f, 0.f, 0.f}

// ---------------------------------------------------------------------------
// Single fused kernel. 256 blocks x 512 threads, block g owns output rows
// 4g..4g+3. Pre-barrier: H1 GEMM for own rows (H1a stays in LDS, H1b -> ws).
// Device-wide release/acquire barrier (all 256 blocks resident by construction:
// LDS ~50KB, VGPR<=256, 512 thr => every CU hosts >=1 block).
// Post-barrier: A-weighted relu-sum over j (the restructured message pass),
// then the three small GEMVs, residual, store.
// ---------------------------------------------------------------------------
__global__ __launch_bounds__(512, 2) void fused_gnn(
    const float* __restrict__ emb,
    const float* __restrict__ coords,
    const float* __restrict__ mW1, const float* __restrict__ mb1,
    const float* __restrict__ mW2, const float* __restrict__ mb2,
    const float* __restrict__ uW1, const float* __restrict__ ub1,
    const float* __restrict__ uW2, const float* __restrict__ ub2,
    float* __restrict__ H1b,
    unsigned* __restrict__ bar,
    float* __restrict__ out)
{
    const int tid  = threadIdx.x;
    const int row0 = blockIdx.x * 4;
    const int b    = row0 >> 8;
    const int i0   = row0 & 255;

    __shared__ f4 red[2048];           // 32 KB, reused by every reduce phase
    __shared__ f4 embT[DD];            // 2 KB : embT[k] = emb[row0+0..3][k]
    __shared__ float cS[NN * 3];       // 3 KB
    __shared__ f4 As4[NN];             // 4 KB : As4[j] = A[0..3][j]
    __shared__ float HaS[4][DD];       // 2 KB : H1a rows (never leaves CU)
    __shared__ f4 R_T[DD];             // 2 KB
    __shared__ f4 U_T[DD + 3];         // 2.1 KB
    __shared__ f4 h_T[DD];             // 2 KB
    __shared__ f4 sAs4[16];
    __shared__ float sAtot[4];
    // total ~49.5 KB

    // ======== pre-barrier: H1 = emb @ [W1a | W1b] for own 4 rows ========
    const int cq1 = tid & 63;              // out col quad (of 256 cols)
    const int kh1 = tid >> 6;              // 0..7 : k-chunk
    const int wq  = cq1 & 31;
    const int wr0 = (cq1 < 32) ? 0 : DD;   // W1a rows 0..127 / W1b rows 128..255
    const f4* __restrict__ W4 = (const f4*)mW1;

    f4 w[16];
    #pragma unroll
    for (int t = 0; t < 16; ++t)
        w[t] = W4[(size_t)(wr0 + kh1 * 16 + t) * 32 + wq];

    {   const int r = tid >> 7, k = tid & 127;
        ((float*)embT)[k * 4 + r] = emb[(size_t)(row0 + r) * DD + k]; }
    const float* __restrict__ cb = coords + (size_t)b * NN * 3;
    if (tid < 192) ((f4*)cS)[tid] = ((const f4*)cb)[tid];
    __syncthreads();

    // A matrix (VALU, overlaps the W1 load latency)
    {   const int j = tid & 255, rA = tid >> 8;
        const float cjx = cS[j * 3], cjy = cS[j * 3 + 1], cjz = cS[j * 3 + 2];
        float* __restrict__ AsF = (float*)As4;
        {   const int ii = i0 + rA;
            const float dx = cjx - cS[ii * 3], dy = cjy - cS[ii * 3 + 1], dz = cjz - cS[ii * 3 + 2];
            AsF[j * 4 + rA] = __expf(-0.5f * (dx * dx + dy * dy + dz * dz)); }
        {   const int ii = i0 + rA + 2;
            const float dx = cjx - cS[ii * 3], dy = cjy - cS[ii * 3 + 1], dz = cjz - cS[ii * 3 + 2];
            AsF[j * 4 + rA + 2] = __expf(-0.5f * (dx * dx + dy * dy + dz * dz)); }
    }

    {   f4 a0 = ZERO4, a1 = ZERO4, a2 = ZERO4, a3 = ZERO4;
        #pragma unroll
        for (int t = 0; t < 16; ++t) {
            const f4 e4 = embT[kh1 * 16 + t];      // wave-uniform b128
            FMA4(a0, e4.x, w[t]);
            FMA4(a1, e4.y, w[t]);
            FMA4(a2, e4.z, w[t]);
            FMA4(a3, e4.w, w[t]);
        }
        red[(kh1 * 4 + 0) * 64 + cq1] = a0;
        red[(kh1 * 4 + 1) * 64 + cq1] = a1;
        red[(kh1 * 4 + 2) * 64 + cq1] = a2;
        red[(kh1 * 4 + 3) * 64 + cq1] = a3;
    }
    __syncthreads();

    {   const float* __restrict__ redF = (const float*)red;
        #pragma unroll
        for (int t = 0; t < 2; ++t) {
            const int o  = t * 512 + tid;
            const int rr = o >> 8, oc = o & 255;
            float v = 0.f;
            #pragma unroll
            for (int q = 0; q < 8; ++q) v += redF[q * 1024 + rr * 256 + oc];
            if (oc < DD) HaS[rr][oc] = v + mb1[oc];                       // H1a -> LDS only
            else         H1b[(size_t)(row0 + rr) * DD + (oc - DD)] = v;   // H1b -> ws
        }
    }

    // prefetch post-phase small operands (free ILP before the fence drains)
    const int rr2 = tid >> 7, ea = tid & 127;
    const float embv = emb[(size_t)(row0 + rr2) * DD + ea];
    const float mb2v = mb2[ea], ub1v = ub1[ea], ub2v = ub2[ea];

    // ======== device-wide barrier (release -> arrive -> spin -> acquire) ====
    __threadfence();                        // per-wave release: drain + L2 wb
    __syncthreads();                        // all waves' fences done
    if (tid == 0) {
        __hip_atomic_fetch_add(bar, 1u, __ATOMIC_RELEASE, __HIP_MEMORY_SCOPE_AGENT);
        while (__hip_atomic_load(bar, __ATOMIC_RELAXED, __HIP_MEMORY_SCOPE_AGENT) < GRID)
            __builtin_amdgcn_s_sleep(2);
        __threadfence();                    // acquire: invalidate stale L1/L2
    }
    __syncthreads();

    // ======== post-barrier: message pass + update MLP ========
    const int eq = tid & 31;           // e-quad (cols 4eq..4eq+3)
    const int js = tid >> 5;           // 0..15 (j-split; doubles as kh in GEMVs)

    const f4 pa0 = ((const f4*)HaS[0])[eq];
    const f4 pa1 = ((const f4*)HaS[1])[eq];
    const f4 pa2 = ((const f4*)HaS[2])[eq];
    const f4 pa3 = ((const f4*)HaS[3])[eq];

    // ---- Phase J: acc[r] = sum_{j in my 16} A[r][j]*relu(pa[r]+h1b[j])
    const f4* __restrict__ Hb4 = (const f4*)(H1b + (size_t)b * NN * DD);
    f4 v[16];
    #pragma unroll
    for (int t = 0; t < 16; ++t) v[t] = Hb4[(size_t)(js * 16 + t) * 32 + eq];

    {   f4 a0 = ZERO4, a1 = ZERO4, a2 = ZERO4, a3 = ZERO4, sA4 = ZERO4;
        #pragma unroll
        for (int t = 0; t < 16; ++t) {
            const f4 a = As4[js * 16 + t];
            sA4.x += a.x; sA4.y += a.y; sA4.z += a.z; sA4.w += a.w;
            FMA4R(a0, a.x, pa0, v[t]);
            FMA4R(a1, a.y, pa1, v[t]);
            FMA4R(a2, a.z, pa2, v[t]);
            FMA4R(a3, a.w, pa3, v[t]);
        }
        red[js * 128 + 0 * 32 + eq] = a0;
        red[js * 128 + 1 * 32 + eq] = a1;
        red[js * 128 + 2 * 32 + eq] = a2;
        red[js * 128 + 3 * 32 + eq] = a3;
        if (eq == 0) sAs4[js] = sA4;
    }
    __syncthreads();

    // ---- Phase R: reduce 16 partials -> R_T ; sAtot
    const float* __restrict__ redF = (const float*)red;
    {   const int r = tid >> 7, e = tid & 127;
        float s = 0.f;
        #pragma unroll
        for (int q = 0; q < 16; ++q) s += redF[q * 512 + r * 128 + e];
        ((float*)R_T)[e * 4 + r] = s;
    }
    if (tid < 4) {
        const float* __restrict__ sF = (const float*)sAs4;
        float s = 0.f;
        #pragma unroll
        for (int q = 0; q < 16; ++q) s += sF[q * 4 + tid];
        sAtot[tid] = s;
    }
    __syncthreads();

    // ---- Phase G1: agg-partials = R @ mW2
    const int cq = eq, kh = js;
    {   const f4* __restrict__ W2g = (const f4*)mW2;
        f4 wv[8];
        #pragma unroll
        for (int t = 0; t < 8; ++t) wv[t] = W2g[(size_t)(kh * 8 + t) * 32 + cq];
        f4 g0 = ZERO4, g1 = ZERO4, g2 = ZERO4, g3 = ZERO4;
        #pragma unroll
        for (int t = 0; t < 8; ++t) {
            const f4 rv = R_T[kh * 8 + t];
            FMA4(g0, rv.x, wv[t]);
            FMA4(g1, rv.y, wv[t]);
            FMA4(g2, rv.z, wv[t]);
            FMA4(g3, rv.w, wv[t]);
        }
        red[kh * 128 + 0 * 32 + cq] = g0;
        red[kh * 128 + 1 * 32 + cq] = g1;
        red[kh * 128 + 2 * 32 + cq] = g2;
        red[kh * 128 + 3 * 32 + cq] = g3;
    }
    __syncthreads();

    // ---- Phase U: reduce + assemble upd_in (agg + sA*mb2; coords tail)
    {   const int r = tid >> 7, e = tid & 127;
        float s = sAtot[r] * mb2v;
        #pragma unroll
        for (int q = 0; q < 16; ++q) s += redF[q * 512 + r * 128 + e];
        ((float*)U_T)[e * 4 + r] = s;
    }
    if (tid < 12) {
        const int r = tid & 3, c = tid >> 2;
        ((float*)U_T)[(DD + c) * 4 + r] = cS[(i0 + r) * 3 + c];
    }
    __syncthreads();

    // ---- Phase G2: hid-partials = upd_in @ uW1 (kh==15 handles 3 tail rows)
    {   const f4* __restrict__ U1g = (const f4*)uW1;
        f4 wv[8];
        #pragma unroll
        for (int t = 0; t < 8; ++t) wv[t] = U1g[(size_t)(kh * 8 + t) * 32 + cq];
        f4 g0 = ZERO4, g1 = ZERO4, g2 = ZERO4, g3 = ZERO4;
        #pragma unroll
        for (int t = 0; t < 8; ++t) {
            const f4 uv = U_T[kh * 8 + t];
            FMA4(g0, uv.x, wv[t]);
            FMA4(g1, uv.y, wv[t]);
            FMA4(g2, uv.z, wv[t]);
            FMA4(g3, uv.w, wv[t]);
        }
        if (kh == 15) {
            #pragma unroll
            for (int t = 0; t < 3; ++t) {
                const f4 wt = U1g[(size_t)(DD + t) * 32 + cq];
                const f4 uv = U_T[DD + t];
                FMA4(g0, uv.x, wt);
                FMA4(g1, uv.y, wt);
                FMA4(g2, uv.z, wt);
                FMA4(g3, uv.w, wt);
            }
        }
        red[kh * 128 + 0 * 32 + cq] = g0;
        red[kh * 128 + 1 * 32 + cq] = g1;
        red[kh * 128 + 2 * 32 + cq] = g2;
        red[kh * 128 + 3 * 32 + cq] = g3;
    }
    __syncthreads();

    // ---- Phase H: reduce + relu -> h_T
    {   const int r = tid >> 7, e = tid & 127;
        float s = ub1v;
        #pragma unroll
        for (int q = 0; q < 16; ++q) s += redF[q * 512 + r * 128 + e];
        ((float*)h_T)[e * 4 + r] = fmaxf(s, 0.f);
    }
    __syncthreads();

    // ---- Phase G3: delta-partials = hid @ uW2
    {   const f4* __restrict__ U2g = (const f4*)uW2;
        f4 wv[8];
        #pragma unroll
        for (int t = 0; t < 8; ++t) wv[t] = U2g[(size_t)(kh * 8 + t) * 32 + cq];
        f4 g0 = ZERO4, g1 = ZERO4, g2 = ZERO4, g3 = ZERO4;
        #pragma unroll
        for (int t = 0; t < 8; ++t) {
            const f4 hv = h_T[kh * 8 + t];
            FMA4(g0, hv.x, wv[t]);
            FMA4(g1, hv.y, wv[t]);
            FMA4(g2, hv.z, wv[t]);
            FMA4(g3, hv.w, wv[t]);
        }
        red[kh * 128 + 0 * 32 + cq] = g0;
        red[kh * 128 + 1 * 32 + cq] = g1;
        red[kh * 128 + 2 * 32 + cq] = g2;
        red[kh * 128 + 3 * 32 + cq] = g3;
    }
    __syncthreads();

    // ---- Final: reduce + residual
    {   const int r = tid >> 7, e = tid & 127;
        float s = ub2v;
        #pragma unroll
        for (int q = 0; q < 16; ++q) s += redF[q * 512 + r * 128 + e];
        out[(size_t)(row0 + r) * DD + e] = embv + s;
    }
}

extern "C" void kernel_launch(void* const* d_in, const int* in_sizes, int n_in,
                              void* d_out, int out_size, void* d_ws, size_t ws_size,
                              hipStream_t stream) {
    const float* emb    = (const float*)d_in[0];
    const float* coords = (const float*)d_in[1];
    const float* mW1    = (const float*)d_in[2];
    const float* mb1    = (const float*)d_in[3];
    const float* mW2    = (const float*)d_in[4];
    const float* mb2    = (const float*)d_in[5];
    const float* uW1    = (const float*)d_in[6];
    const float* ub1    = (const float*)d_in[7];
    const float* uW2    = (const float*)d_in[8];
    const float* ub2    = (const float*)d_in[9];
    float* out = (float*)d_out;

    unsigned* bar = (unsigned*)d_ws;                    // barrier counter
    float* H1b = (float*)((char*)d_ws + 256);           // 0.5 MB H1b workspace

    hipMemsetAsync(d_ws, 0, 256, stream);               // re-zero barrier each launch
    fused_gnn<<<dim3(GRID), dim3(512), 0, stream>>>(
        emb, coords, mW1, mb1, mW2, mb2, uW1, ub1, uW2, ub2, H1b, bar, out);
}

// Round 6
// 83.532 us; speedup vs baseline: 1.5998x; 1.5998x over previous
//
#include <hip/hip_runtime.h>
#include <math.h>

#define NN 256
#define DD 128

typedef float4 f4;
typedef float2 f2;

// acc += s * v (componentwise)
#define FMA4(acc, s, v)                          \
  acc.x = fmaf(s, v.x, acc.x);                   \
  acc.y = fmaf(s, v.y, acc.y);                   \
  acc.z = fmaf(s, v.z, acc.z);                   \
  acc.w = fmaf(s, v.w, acc.w);

// acc += a * relu(p + v)
#define FMA4R(acc, a, p, v)                              \
  acc.x = fmaf(a, fmaxf(p.x + v.x, 0.f), acc.x);         \
  acc.y = fmaf(a, fmaxf(p.y + v.y, 0.f), acc.y);         \
  acc.z = fmaf(a, fmaxf(p.z + v.z, 0.f), acc.z);         \
  acc.w = fmaf(a, fmaxf(p.w + v.w, 0.f), acc.w);

#define ZERO4 {0.f, 0.f, 0.f, 0.f}

// ---------------------------------------------------------------------------
// h1_kernel: H1a = emb@W1a + mb1 ; H1b = emb@W1b
// 512 blocks x 256 threads, 2 rows/block (2 blocks/CU for latency overlap).
// thread = (cq 0..63 : col-quad of 256 cols, kh 0..3 : 32-k chunk).
// ---------------------------------------------------------------------------
__global__ __launch_bounds__(256, 2) void h1_kernel(
    const float* __restrict__ emb,   // [1024][128]
    const float* __restrict__ mW1,   // [256][128]
    const float* __restrict__ mb1,   // [128]
    float* __restrict__ H1a,
    float* __restrict__ H1b)
{
    const int tid  = threadIdx.x;
    const int row0 = blockIdx.x * 2;

    __shared__ f2 embT[DD];          // 1 KB : embT[k] = {emb[row0][k], emb[row0+1][k]}
    __shared__ f4 red[4 * 2 * 64];   // 8 KB : [kh][r][cq]

    const int cq  = tid & 63;
    const int kh  = tid >> 6;                // 0..3, k in [32kh, 32kh+32)
    const int wq  = cq & 31;
    const int wr0 = (cq < 32) ? 0 : DD;      // W1a rows 0..127 / W1b rows 128..255
    const f4* __restrict__ W4 = (const f4*)mW1;

    // issue all 32 weight loads up front (128 VGPR, statically indexed)
    f4 w[32];
    #pragma unroll
    for (int t = 0; t < 32; ++t)
        w[t] = W4[(size_t)(wr0 + kh * 32 + t) * 32 + wq];

    {   const int r = tid >> 7, k = tid & 127;
        ((float*)embT)[k * 2 + r] = emb[(size_t)(row0 + r) * DD + k]; }
    __syncthreads();

    f4 a0 = ZERO4, a1 = ZERO4;
    #pragma unroll
    for (int t = 0; t < 32; ++t) {
        const f2 e4 = embT[kh * 32 + t];     // wave-uniform b64 broadcast
        FMA4(a0, e4.x, w[t]);
        FMA4(a1, e4.y, w[t]);
    }
    red[(kh * 2 + 0) * 64 + cq] = a0;
    red[(kh * 2 + 1) * 64 + cq] = a1;
    __syncthreads();

    const float* __restrict__ redF = (const float*)red;
    #pragma unroll
    for (int t = 0; t < 2; ++t) {
        const int o  = t * 256 + tid;
        const int rr = o >> 8, oc = o & 255;
        float v = 0.f;
        #pragma unroll
        for (int q = 0; q < 4; ++q) v += redF[(q * 2 + rr) * 256 + oc];
        if (oc < DD) H1a[(size_t)(row0 + rr) * DD + oc]        = v + mb1[oc];
        else         H1b[(size_t)(row0 + rr) * DD + (oc - DD)] = v;
    }
}

// ---------------------------------------------------------------------------
// gnn_kernel: 512 blocks x 256 threads, 2 output rows/block (2 blocks/CU).
// thread = (eq 0..31 : e-quad, js 0..7 : 32-j / 16-k chunk).
// Weight loads for each GEMV issued at the end of the previous phase so the
// latency hides under the LDS reduce.
// ---------------------------------------------------------------------------
__global__ __launch_bounds__(256, 2) void gnn_kernel(
    const float* __restrict__ emb,
    const float* __restrict__ coords,  // [B][256][3]
    const float* __restrict__ mW2, const float* __restrict__ mb2,
    const float* __restrict__ uW1, const float* __restrict__ ub1,
    const float* __restrict__ uW2, const float* __restrict__ ub2,
    const float* __restrict__ H1a, const float* __restrict__ H1b,
    float* __restrict__ out)
{
    const int tid  = threadIdx.x;
    const int row0 = blockIdx.x * 2;
    const int b    = row0 >> 8;
    const int i0   = row0 & 255;

    __shared__ float cS[NN * 3];       // 3 KB
    __shared__ f2 A2[NN];              // 2 KB : A2[j] = {A[row0][j], A[row0+1][j]}
    __shared__ f4 red[8 * 2 * 32];     // 8 KB : [js][r][eq]
    __shared__ f2 R_T[DD];             // 1 KB
    __shared__ f2 U_T[DD + 3];
    __shared__ f2 h_T[DD];
    __shared__ f2 sAs2[8];
    __shared__ float sAtot[2];

    const int eq = tid & 31;
    const int js = tid >> 5;           // 0..7

    // early independent global loads
    const f4* __restrict__ Ha4 = (const f4*)(H1a + (size_t)row0 * DD);
    const f4 pa0 = Ha4[0 * 32 + eq];
    const f4 pa1 = Ha4[1 * 32 + eq];
    const int rr2 = tid >> 7, ea = tid & 127;
    const float embv = emb[(size_t)(row0 + rr2) * DD + ea];
    const float mb2v = mb2[ea], ub1v = ub1[ea], ub2v = ub2[ea];

    // H1b stream for my 32 j's (32 x 16B, statically indexed, all in flight)
    const f4* __restrict__ Hb4 = (const f4*)(H1b + (size_t)b * NN * DD);
    f4 v[32];
    #pragma unroll
    for (int t = 0; t < 32; ++t) v[t] = Hb4[(size_t)(js * 32 + t) * 32 + eq];

    // stage coords
    const float* __restrict__ cb = coords + (size_t)b * NN * 3;
    if (tid < 192) ((f4*)cS)[tid] = ((const f4*)cb)[tid];
    __syncthreads();

    // A rows (thread j = tid computes both rows)
    {   const int j = tid;
        const float cjx = cS[j * 3], cjy = cS[j * 3 + 1], cjz = cS[j * 3 + 2];
        float dx = cjx - cS[i0 * 3], dy = cjy - cS[i0 * 3 + 1], dz = cjz - cS[i0 * 3 + 2];
        const float a0 = __expf(-0.5f * (dx * dx + dy * dy + dz * dz));
        dx = cjx - cS[(i0 + 1) * 3]; dy = cjy - cS[(i0 + 1) * 3 + 1]; dz = cjz - cS[(i0 + 1) * 3 + 2];
        const float a1 = __expf(-0.5f * (dx * dx + dy * dy + dz * dz));
        A2[j] = {a0, a1};
    }
    __syncthreads();

    // ---- Phase J: acc[r] += A[r][j] * relu(pa[r] + h1b[j]) over my 32 j's
    {   f4 a0 = ZERO4, a1 = ZERO4;
        f2 sA = {0.f, 0.f};
        #pragma unroll
        for (int t = 0; t < 32; ++t) {
            const f2 a = A2[js * 32 + t];      // uniform per js-group (broadcast)
            sA.x += a.x; sA.y += a.y;
            FMA4R(a0, a.x, pa0, v[t]);
            FMA4R(a1, a.y, pa1, v[t]);
        }
        red[(js * 2 + 0) * 32 + eq] = a0;
        red[(js * 2 + 1) * 32 + eq] = a1;
        if (eq == 0) sAs2[js] = sA;
    }

    // issue G1 weights now (latency hides under Phase R)
    const int kh = js, cq = eq;
    f4 wv[16];
    {   const f4* __restrict__ W2g = (const f4*)mW2;
        #pragma unroll
        for (int t = 0; t < 16; ++t) wv[t] = W2g[(size_t)(kh * 16 + t) * 32 + cq];
    }
    __syncthreads();

    // ---- Phase R: reduce 8 partials -> R_T ; sAtot
    const float* __restrict__ redF = (const float*)red;
    {   const int r = tid >> 7, e = tid & 127;
        float s = 0.f;
        #pragma unroll
        for (int q = 0; q < 8; ++q) s += redF[(q * 2 + r) * 128 + e];
        ((float*)R_T)[e * 2 + r] = s;
    }
    if (tid < 2) {
        const float* __restrict__ sF = (const float*)sAs2;
        float s = 0.f;
        #pragma unroll
        for (int q = 0; q < 8; ++q) s += sF[q * 2 + tid];
        sAtot[tid] = s;
    }
    __syncthreads();

    // ---- Phase G1: agg-partials = R @ mW2
    {   f4 g0 = ZERO4, g1 = ZERO4;
        #pragma unroll
        for (int t = 0; t < 16; ++t) {
            const f2 rv = R_T[kh * 16 + t];    // broadcast
            FMA4(g0, rv.x, wv[t]);
            FMA4(g1, rv.y, wv[t]);
        }
        red[(kh * 2 + 0) * 32 + cq] = g0;
        red[(kh * 2 + 1) * 32 + cq] = g1;
    }
    // issue G2 weights (hide under Phase U)
    {   const f4* __restrict__ U1g = (const f4*)uW1;
        #pragma unroll
        for (int t = 0; t < 16; ++t) wv[t] = U1g[(size_t)(kh * 16 + t) * 32 + cq];
    }
    __syncthreads();

    // ---- Phase U: reduce + assemble upd_in (agg + sA*mb2; coords tail)
    {   const int r = tid >> 7, e = tid & 127;
        float s = sAtot[r] * mb2v;
        #pragma unroll
        for (int q = 0; q < 8; ++q) s += redF[(q * 2 + r) * 128 + e];
        ((float*)U_T)[e * 2 + r] = s;
    }
    if (tid < 6) {
        const int r = tid & 1, c = tid >> 1;
        ((float*)U_T)[(DD + c) * 2 + r] = cS[(i0 + r) * 3 + c];
    }
    __syncthreads();

    // ---- Phase G2: hid-partials = upd_in @ uW1 (kh==7 handles 3 tail rows)
    {   f4 g0 = ZERO4, g1 = ZERO4;
        #pragma unroll
        for (int t = 0; t < 16; ++t) {
            const f2 uv = U_T[kh * 16 + t];
            FMA4(g0, uv.x, wv[t]);
            FMA4(g1, uv.y, wv[t]);
        }
        if (kh == 7) {
            const f4* __restrict__ U1g = (const f4*)uW1;
            #pragma unroll
            for (int t = 0; t < 3; ++t) {
                const f4 wt = U1g[(size_t)(DD + t) * 32 + cq];
                const f2 uv = U_T[DD + t];
                FMA4(g0, uv.x, wt);
                FMA4(g1, uv.y, wt);
            }
        }
        red[(kh * 2 + 0) * 32 + cq] = g0;
        red[(kh * 2 + 1) * 32 + cq] = g1;
    }
    // issue G3 weights (hide under Phase H)
    {   const f4* __restrict__ U2g = (const f4*)uW2;
        #pragma unroll
        for (int t = 0; t < 16; ++t) wv[t] = U2g[(size_t)(kh * 16 + t) * 32 + cq];
    }
    __syncthreads();

    // ---- Phase H: reduce + relu -> h_T
    {   const int r = tid >> 7, e = tid & 127;
        float s = ub1v;
        #pragma unroll
        for (int q = 0; q < 8; ++q) s += redF[(q * 2 + r) * 128 + e];
        ((float*)h_T)[e * 2 + r] = fmaxf(s, 0.f);
    }
    __syncthreads();

    // ---- Phase G3: delta-partials = hid @ uW2
    {   f4 g0 = ZERO4, g1 = ZERO4;
        #pragma unroll
        for (int t = 0; t < 16; ++t) {
            const f2 hv = h_T[kh * 16 + t];
            FMA4(g0, hv.x, wv[t]);
            FMA4(g1, hv.y, wv[t]);
        }
        red[(kh * 2 + 0) * 32 + cq] = g0;
        red[(kh * 2 + 1) * 32 + cq] = g1;
    }
    __syncthreads();

    // ---- Final: reduce + residual
    {   const int r = tid >> 7, e = tid & 127;
        float s = ub2v;
        #pragma unroll
        for (int q = 0; q < 8; ++q) s += redF[(q * 2 + r) * 128 + e];
        out[(size_t)(row0 + r) * DD + e] = embv + s;
    }
}

extern "C" void kernel_launch(void* const* d_in, const int* in_sizes, int n_in,
                              void* d_out, int out_size, void* d_ws, size_t ws_size,
                              hipStream_t stream) {
    const float* emb    = (const float*)d_in[0];
    const float* coords = (const float*)d_in[1];
    const float* mW1    = (const float*)d_in[2];
    const float* mb1    = (const float*)d_in[3];
    const float* mW2    = (const float*)d_in[4];
    const float* mb2    = (const float*)d_in[5];
    const float* uW1    = (const float*)d_in[6];
    const float* ub1    = (const float*)d_in[7];
    const float* uW2    = (const float*)d_in[8];
    const float* ub2    = (const float*)d_in[9];
    float* out = (float*)d_out;

    float* H1a = (float*)d_ws;
    float* H1b = H1a + 4 * NN * DD;

    h1_kernel<<<dim3(512), dim3(256), 0, stream>>>(emb, mW1, mb1, H1a, H1b);
    gnn_kernel<<<dim3(512), dim3(256), 0, stream>>>(
        emb, coords, mW2, mb2, uW1, ub1, uW2, ub2, H1a, H1b, out);
}